// Round 4
// baseline (17402.426 us; speedup 1.0000x reference)
//
#include <hip/hip_runtime.h>
#include <hip/hip_bf16.h>
#include <stdint.h>

// BayesGRU eval: T=512, B=64, D_IN=1024, D_H=1024.
// Persistent kernel, 128 WGs (1/CU), weights LDS-resident, NO grid barriers:
// per-(step,row-block) producer counters + LLC-bypass data transport.
// Every wave runs autonomously (no __syncthreads in the main loop).

#define T_STEPS 512
#define BATCH   64
#define DIN     1024
#define DH      1024
#define NWG     128

typedef __attribute__((ext_vector_type(8))) short bf16x8;
typedef __attribute__((ext_vector_type(4))) float f32x4;

static __device__ __forceinline__ unsigned short f2bf(float x) {
    union { float f; uint32_t u; } v; v.f = x;
    uint32_t u = v.u;
    return (unsigned short)((u + 0x7FFFu + ((u >> 16) & 1u)) >> 16);
}
static __device__ __forceinline__ float bf2f(unsigned u) {
    union { uint32_t v; float f; } x; x.v = u << 16; return x.f;
}

// ---- LLC-coherent transport (bypass L1/L2 on both sides) -------------------
static __device__ __forceinline__ void st_wt_u16(void* p, unsigned v) {
    asm volatile("global_store_short %0, %1, off sc0 sc1" :: "v"(p), "v"(v) : "memory");
}
static __device__ __forceinline__ void st_wt_u64(void* p, unsigned long long v) {
    asm volatile("global_store_dwordx2 %0, %1, off sc0 sc1" :: "v"(p), "v"(v) : "memory");
}
static __device__ __forceinline__ bf16x8 ld_llc(const unsigned short* p) {
    bf16x8 r;
    asm volatile("global_load_dwordx4 %0, %1, off sc0 sc1" : "=v"(r) : "v"(p));
    return r;
}
static __device__ __forceinline__ unsigned ld_llc_u16(const unsigned short* p) {
    unsigned r;
    asm volatile("global_load_ushort %0, %1, off sc0 sc1" : "=v"(r) : "v"(p));
    return r;
}
static __device__ __forceinline__ void vwait0() {
    asm volatile("s_waitcnt vmcnt(0)" ::: "memory");
    __builtin_amdgcn_sched_barrier(0);   // rule #18: keep MFMA from hoisting past the wait
}
static __device__ __forceinline__ void wait_cnt(const int* c) {
    while (__hip_atomic_load(c, __ATOMIC_RELAXED, __HIP_MEMORY_SCOPE_AGENT) < 64)
        __builtin_amdgcn_s_sleep(2);
}
static __device__ __forceinline__ void post_cnt(int* c, int lane) {
    asm volatile("s_waitcnt vmcnt(0)" ::: "memory");   // data stores retired at LLC
    if (lane == 0)
        __hip_atomic_fetch_add(c, 1, __ATOMIC_RELAXED, __HIP_MEMORY_SCOPE_AGENT);
}

// ---------------- weight packing (layout verified rounds 1-3) ---------------
// Wur: [kk=64][wg=128][kg=4][col=16][8] (u cols: wg<64, r cols: wg>=64)
// Wc : [kk=64][wg=64 ][kg=4][col=16][8], K order = [x | h] for all gates.
__global__ __launch_bounds__(256) void gru_pack_weights(
    const float* __restrict__ wihu, const float* __restrict__ wihr,
    const float* __restrict__ wihc, const float* __restrict__ whhu,
    const float* __restrict__ whhr, const float* __restrict__ whhc,
    unsigned short* __restrict__ Wur, unsigned short* __restrict__ Wc)
{
    const int total = 3072 * 2048;
    for (int idx = blockIdx.x * 256 + threadIdx.x; idx < total; idx += gridDim.x * 256) {
        int n = idx >> 11;        // 0..3071
        int k = idx & 2047;
        int j = n & 1023;
        float v;
        if (n < 1024)      v = (k < DIN) ? wihu[j*DIN + k] : whhu[j*DH + (k - DIN)];
        else if (n < 2048) v = (k < DIN) ? wihr[j*DIN + k] : whhr[j*DH + (k - DIN)];
        else               v = (k < DIN) ? wihc[j*DIN + k] : whhc[j*DH + (k - DIN)];
        unsigned short bv = f2bf(v);
        int kk = k >> 5, kg = (k >> 3) & 3, r = k & 7;
        if (n < 2048) {
            int b = n >> 4, col = n & 15;
            Wur[((((size_t)kk*128 + b)*4 + kg)*16 + col)*8 + r] = bv;
        } else {
            int nc = n - 2048, b = nc >> 4, col = nc & 15;
            Wc [((((size_t)kk*64 + b)*4 + kg)*16 + col)*8 + r] = bv;
        }
    }
}

// ---------------- init: xA[0]=bf16(x_0), hA[0]=bf16(h0), counters=0 ---------
__global__ __launch_bounds__(256) void gru_init(
    const float* __restrict__ emb, const float* __restrict__ hx,
    unsigned short* __restrict__ xA, unsigned short* __restrict__ hA,
    int* __restrict__ cnt)
{
    int i = blockIdx.x * 256 + threadIdx.x;   // grid 256x256 = 65536
    xA[i] = f2bf(emb[i]);
    hA[i] = f2bf(hx[i]);
    if (i < 6144) cnt[i] = 0;
}

// ---------------- persistent GRU kernel -------------------------------------
// c-WG (wg<64): wave wid owns rows [16wid,16wid+16) x cols [16wg,16wg+16):
//   computes u (K=2048) and cell (K=2048 over [x|rst*h]) and the h-update.
// r-WG (wg>=64): same slab shape for the r gate; then x_{t+1} f32->bf16.
// Counter families (64 producers each): H[t][wid] (h_t slabs), R[t][wid]
// (rh slabs), X[t][wid] (x_t slabs). All waves fully autonomous.
__global__ __launch_bounds__(256, 1) void gru_persistent(
    const unsigned short* __restrict__ Wur, const unsigned short* __restrict__ Wc,
    const float* __restrict__ emb, const float* __restrict__ hx,
    const float* __restrict__ bu, const float* __restrict__ br, const float* __restrict__ bc,
    unsigned short* __restrict__ xA, unsigned short* __restrict__ hA,
    unsigned short* __restrict__ rh, float* __restrict__ out, int* __restrict__ cnt)
{
    __shared__ unsigned short wur_s[32768];   // 64 KB: this WG's 16-col u/r slice
    __shared__ unsigned short wc_s [32768];   // 64 KB: c-WGs' 16-col c slice

    const int wg   = blockIdx.x;
    const int tid  = threadIdx.x;
    const int lane = tid & 63;
    const int wid  = tid >> 6;
    const int m0   = wid * 16;
    const int c15  = lane & 15;
    const int kg   = lane >> 4;

    for (int i = tid; i < 4096; i += 256) {
        int kk = i >> 6, j = i & 63;
        *((uint4*)wur_s + i) =
            *(const uint4*)((const char*)Wur + ((size_t)kk*128 + wg)*1024 + j*16);
    }
    if (wg < 64) {
        for (int i = tid; i < 4096; i += 256) {
            int kk = i >> 6, j = i & 63;
            *((uint4*)wc_s + i) =
                *(const uint4*)((const char*)Wc + ((size_t)kk*64 + wg)*1024 + j*16);
        }
    }
    __syncthreads();          // last sync — waves are autonomous below

    const int v    = wg & 63;
    const int colj = v * 16 + c15;

    int* Hc = cnt;            // [512][4]
    int* Rc = cnt + 2048;     // [512][4]
    int* Xc = cnt + 4096;     // [512][4]

    if (wg < 64) {
        // ================= c-path: u + cell + h-update =================
        const float bu_ = bu[colj], bc_ = bc[colj];
        float hreg[4];
        #pragma unroll
        for (int i = 0; i < 4; ++i) hreg[i] = hx[(m0 + kg*4 + i) * DH + colj];

        for (int t = 0; t < T_STEPS; ++t) {
            const int par = t & 1;
            const unsigned short* xa   = xA + par * 65536;
            const unsigned short* ha   = hA + par * 65536;
            unsigned short*       hnxt = hA + (par ^ 1) * 65536;

            f32x4 au = {0.f,0.f,0.f,0.f}, ac = {0.f,0.f,0.f,0.f};
            bf16x8 fr[32];

            // --- x-parts of u and c (off critical path) ---
            if (t > 0) wait_cnt(Xc + t*4 + wid);
            {
                const unsigned short* ap = xa + (m0 + c15) * DIN + kg * 8;
                #pragma unroll
                for (int kk = 0; kk < 32; ++kk) fr[kk] = ld_llc(ap + kk * 32);
                vwait0();
                #pragma unroll
                for (int kk = 0; kk < 32; ++kk) {
                    bf16x8 b0 = *(const bf16x8*)(wur_s + kk * 512 + lane * 8);
                    au = __builtin_amdgcn_mfma_f32_16x16x32_bf16(fr[kk], b0, au, 0, 0, 0);
                    bf16x8 b1 = *(const bf16x8*)(wc_s + kk * 512 + lane * 8);
                    ac = __builtin_amdgcn_mfma_f32_16x16x32_bf16(fr[kk], b1, ac, 0, 0, 0);
                }
            }

            // --- h-part of u ---
            if (t > 0) wait_cnt(Hc + (t-1)*4 + wid);
            {
                const unsigned short* ap = ha + (m0 + c15) * DH + kg * 8;
                #pragma unroll
                for (int kk = 0; kk < 32; ++kk) fr[kk] = ld_llc(ap + kk * 32);
                vwait0();
                #pragma unroll
                for (int kk = 0; kk < 32; ++kk) {
                    bf16x8 b0 = *(const bf16x8*)(wur_s + (kk + 32) * 512 + lane * 8);
                    au = __builtin_amdgcn_mfma_f32_16x16x32_bf16(fr[kk], b0, au, 0, 0, 0);
                }
            }
            float ureg[4];
            #pragma unroll
            for (int i = 0; i < 4; ++i)
                ureg[i] = 1.f / (1.f + __expf(-(au[i] + bu_)));

            // --- rh-part of cell ---
            wait_cnt(Rc + t*4 + wid);
            {
                const unsigned short* ap = rh + (m0 + c15) * DH + kg * 8;
                #pragma unroll
                for (int kk = 0; kk < 32; ++kk) fr[kk] = ld_llc(ap + kk * 32);
                vwait0();
                #pragma unroll
                for (int kk = 0; kk < 32; ++kk) {
                    bf16x8 b1 = *(const bf16x8*)(wc_s + (kk + 32) * 512 + lane * 8);
                    ac = __builtin_amdgcn_mfma_f32_16x16x32_bf16(fr[kk], b1, ac, 0, 0, 0);
                }
            }

            // --- update + publish h ---
            float* out_t = out + (size_t)t * (BATCH * DH);
            #pragma unroll
            for (int i = 0; i < 4; ++i) {
                int row = m0 + kg * 4 + i;
                float pre = ac[i] + bc_;
                float e   = __expf(2.f * pre);
                float cel = 1.f - 2.f / (e + 1.f);          // tanh
                float hn  = (1.f - ureg[i]) * hreg[i] + ureg[i] * cel;
                hreg[i] = hn;
                out_t[row * DH + colj] = hn;                // normal store
                st_wt_u16(hnxt + row * DH + colj, (unsigned)f2bf(hn));
                if (t == T_STEPS - 1)
                    out[(size_t)T_STEPS * BATCH * DH + row * DH + colj] = hn;
            }
            post_cnt(Hc + t*4 + wid, lane);
        }
    } else {
        // ================= r-path: reset gate + x conversion =================
        const float br_ = br[colj];
        for (int t = 0; t < T_STEPS; ++t) {
            const int par = t & 1;
            const unsigned short* xa = xA + par * 65536;
            const unsigned short* ha = hA + par * 65536;

            f32x4 ar = {0.f,0.f,0.f,0.f};
            bf16x8 fr[32];

            // --- x-part of r ---
            if (t > 0) wait_cnt(Xc + t*4 + wid);
            {
                const unsigned short* ap = xa + (m0 + c15) * DIN + kg * 8;
                #pragma unroll
                for (int kk = 0; kk < 32; ++kk) fr[kk] = ld_llc(ap + kk * 32);
                vwait0();
                #pragma unroll
                for (int kk = 0; kk < 32; ++kk) {
                    bf16x8 b0 = *(const bf16x8*)(wur_s + kk * 512 + lane * 8);
                    ar = __builtin_amdgcn_mfma_f32_16x16x32_bf16(fr[kk], b0, ar, 0, 0, 0);
                }
            }

            // --- h-part of r (+ h values for the rst*h product) ---
            if (t > 0) wait_cnt(Hc + (t-1)*4 + wid);
            unsigned hp16[4];
            {
                const unsigned short* ap = ha + (m0 + c15) * DH + kg * 8;
                #pragma unroll
                for (int kk = 0; kk < 32; ++kk) fr[kk] = ld_llc(ap + kk * 32);
                #pragma unroll
                for (int i = 0; i < 4; ++i)
                    hp16[i] = ld_llc_u16(ha + (m0 + kg*4 + i) * DH + colj);
                vwait0();
                #pragma unroll
                for (int kk = 0; kk < 32; ++kk) {
                    bf16x8 b0 = *(const bf16x8*)(wur_s + (kk + 32) * 512 + lane * 8);
                    ar = __builtin_amdgcn_mfma_f32_16x16x32_bf16(fr[kk], b0, ar, 0, 0, 0);
                }
            }

            // --- publish rh slab ---
            #pragma unroll
            for (int i = 0; i < 4; ++i) {
                int row = m0 + kg * 4 + i;
                float s = 1.f / (1.f + __expf(-(ar[i] + br_)));
                st_wt_u16(rh + row * DH + colj, (unsigned)f2bf(s * bf2f(hp16[i])));
            }
            post_cnt(Rc + t*4 + wid, lane);

            // --- x_{t+1} conversion (off critical path) ---
            if (t + 1 < T_STEPS) {
                int row = m0 + (lane >> 2);
                int c4  = (lane & 3) * 4;
                const float* src = emb + ((size_t)(t + 1) * BATCH + row) * DIN + v * 16 + c4;
                float4 xv = *(const float4*)src;            // normal load (read-only input)
                unsigned long long pk =
                      (unsigned long long)f2bf(xv.x)
                    | ((unsigned long long)f2bf(xv.y) << 16)
                    | ((unsigned long long)f2bf(xv.z) << 32)
                    | ((unsigned long long)f2bf(xv.w) << 48);
                st_wt_u64(xA + (par ^ 1) * 65536 + row * DIN + v * 16 + c4, pk);
                post_cnt(Xc + (t+1)*4 + wid, lane);
            }
        }
    }
}

// ---------------- host launch ----------------------------------------------
extern "C" void kernel_launch(void* const* d_in, const int* in_sizes, int n_in,
                              void* d_out, int out_size, void* d_ws, size_t ws_size,
                              hipStream_t stream)
{
    const float* emb  = (const float*)d_in[0];
    const float* hx   = (const float*)d_in[1];
    const float* wihu = (const float*)d_in[2];
    const float* wihr = (const float*)d_in[3];
    const float* wihc = (const float*)d_in[4];
    const float* whhu = (const float*)d_in[5];
    const float* whhr = (const float*)d_in[6];
    const float* whhc = (const float*)d_in[7];
    const float* bu   = (const float*)d_in[8];
    const float* br   = (const float*)d_in[9];
    const float* bc   = (const float*)d_in[10];
    float* out = (float*)d_out;
    char*  ws  = (char*)d_ws;

    // ws layout (bytes); total 13,262,848 (< 13.76 MB proven in round 0)
    unsigned short* Wur = (unsigned short*)(ws + 0);          // 8 MiB
    unsigned short* Wc  = (unsigned short*)(ws + 8388608);    // 4 MiB
    unsigned short* xA  = (unsigned short*)(ws + 12582912);   // 256 KiB (2 buffers)
    unsigned short* hA  = (unsigned short*)(ws + 12845056);   // 256 KiB (2 buffers)
    unsigned short* rhb = (unsigned short*)(ws + 13107200);   // 128 KiB
    int*            cnt = (int*)(ws + 13238272);              // 24 KiB

    gru_pack_weights<<<1024, 256, 0, stream>>>(wihu, wihr, wihc, whhu, whhr, whhc, Wur, Wc);
    gru_init<<<256, 256, 0, stream>>>(emb, hx, xA, hA, cnt);
    gru_persistent<<<NWG, 256, 0, stream>>>(Wur, Wc, emb, hx, bu, br, bc,
                                            xA, hA, rhb, out, cnt);
}

// Round 5
// 8480.273 us; speedup vs baseline: 2.0521x; 2.0521x over previous
//
#include <hip/hip_runtime.h>
#include <hip/hip_bf16.h>
#include <stdint.h>

// BayesGRU eval: T=512, B=64, D_IN=1024, D_H=1024.
// Persistent kernel, 128 WGs (1/CU), weights LDS-resident, fence-free
// LLC-coherent transport, per-step flag lines with LOW-CONTENTION topology:
//   line(t,g) = 64B, g=0..7:  dword0 = H (quota 8, per-WG posts)
//                             dword1 = Rlo (quota 4)  dword2 = Rhi (quota 4)
//                             dword3 = X (quota 8)

#define T_STEPS 512
#define BATCH   64
#define DIN     1024
#define DH      1024
#define NWG     128

typedef __attribute__((ext_vector_type(8))) short bf16x8;
typedef __attribute__((ext_vector_type(4))) float f32x4;

static __device__ __forceinline__ unsigned short f2bf(float x) {
    union { float f; uint32_t u; } v; v.f = x;
    uint32_t u = v.u;
    return (unsigned short)((u + 0x7FFFu + ((u >> 16) & 1u)) >> 16);
}
static __device__ __forceinline__ float bf2f(unsigned u) {
    union { uint32_t v; float f; } x; x.v = u << 16; return x.f;
}

// ---- LLC-coherent transport (bypass L1/L2 both sides; no fences ever) ------
static __device__ __forceinline__ void st_wt_u16(void* p, unsigned v) {
    asm volatile("global_store_short %0, %1, off sc0 sc1" :: "v"(p), "v"(v) : "memory");
}
static __device__ __forceinline__ void st_wt_u64(void* p, unsigned long long v) {
    asm volatile("global_store_dwordx2 %0, %1, off sc0 sc1" :: "v"(p), "v"(v) : "memory");
}
static __device__ __forceinline__ bf16x8 ld_llc(const unsigned short* p) {
    bf16x8 r;
    asm volatile("global_load_dwordx4 %0, %1, off sc0 sc1" : "=v"(r) : "v"(p));
    return r;
}
static __device__ __forceinline__ unsigned ld_llc_u16(const unsigned short* p) {
    unsigned r;
    asm volatile("global_load_ushort %0, %1, off sc0 sc1" : "=v"(r) : "v"(p));
    return r;
}
static __device__ __forceinline__ void vwait0() {
    asm volatile("s_waitcnt vmcnt(0)" ::: "memory");
    __builtin_amdgcn_sched_barrier(0);   // rule #18
}

// ---- flag wait/post ---------------------------------------------------------
// cnt line (t,g) = cnt + t*128 + g*16 ints; fam in dword [0..3].
static __device__ __forceinline__ void wait_fam(const int* cnt, int t, int fam, int quota) {
    const int* b = cnt + t * 128 + fam;
    for (;;) {
        int a0,a1,a2,a3,a4,a5,a6,a7;
        asm volatile("global_load_dword %0, %1, off sc0 sc1" : "=v"(a0) : "v"(b));
        asm volatile("global_load_dword %0, %1, off sc0 sc1" : "=v"(a1) : "v"(b+16));
        asm volatile("global_load_dword %0, %1, off sc0 sc1" : "=v"(a2) : "v"(b+32));
        asm volatile("global_load_dword %0, %1, off sc0 sc1" : "=v"(a3) : "v"(b+48));
        asm volatile("global_load_dword %0, %1, off sc0 sc1" : "=v"(a4) : "v"(b+64));
        asm volatile("global_load_dword %0, %1, off sc0 sc1" : "=v"(a5) : "v"(b+80));
        asm volatile("global_load_dword %0, %1, off sc0 sc1" : "=v"(a6) : "v"(b+96));
        asm volatile("global_load_dword %0, %1, off sc0 sc1" : "=v"(a7) : "v"(b+112));
        asm volatile("s_waitcnt vmcnt(0)" ::: "memory");
        __builtin_amdgcn_sched_barrier(0);
        if (a0>=quota && a1>=quota && a2>=quota && a3>=quota &&
            a4>=quota && a5>=quota && a6>=quota && a7>=quota) break;
        __builtin_amdgcn_s_sleep(1);
    }
}
static __device__ __forceinline__ void post_fam(int* cnt, int t, int g, int fam) {
    __hip_atomic_fetch_add(cnt + t * 128 + g * 16 + fam, 1,
                           __ATOMIC_RELAXED, __HIP_MEMORY_SCOPE_AGENT);
}

// ---------------- weight packing (layout verified rounds 1-4) ---------------
__global__ __launch_bounds__(256) void gru_pack_weights(
    const float* __restrict__ wihu, const float* __restrict__ wihr,
    const float* __restrict__ wihc, const float* __restrict__ whhu,
    const float* __restrict__ whhr, const float* __restrict__ whhc,
    unsigned short* __restrict__ Wur, unsigned short* __restrict__ Wc)
{
    const int total = 3072 * 2048;
    for (int idx = blockIdx.x * 256 + threadIdx.x; idx < total; idx += gridDim.x * 256) {
        int n = idx >> 11;        // 0..3071
        int k = idx & 2047;
        int j = n & 1023;
        float v;
        if (n < 1024)      v = (k < DIN) ? wihu[j*DIN + k] : whhu[j*DH + (k - DIN)];
        else if (n < 2048) v = (k < DIN) ? wihr[j*DIN + k] : whhr[j*DH + (k - DIN)];
        else               v = (k < DIN) ? wihc[j*DIN + k] : whhc[j*DH + (k - DIN)];
        unsigned short bv = f2bf(v);
        int kk = k >> 5, kg = (k >> 3) & 3, r = k & 7;
        if (n < 2048) {
            int b = n >> 4, col = n & 15;
            Wur[((((size_t)kk*128 + b)*4 + kg)*16 + col)*8 + r] = bv;
        } else {
            int nc = n - 2048, b = nc >> 4, col = nc & 15;
            Wc [((((size_t)kk*64 + b)*4 + kg)*16 + col)*8 + r] = bv;
        }
    }
}

// ---------------- init: xA[0]=bf16(x_0), hA[0]=bf16(h0), counters=0 ---------
__global__ __launch_bounds__(256) void gru_init(
    const float* __restrict__ emb, const float* __restrict__ hx,
    unsigned short* __restrict__ xA, unsigned short* __restrict__ hA,
    int* __restrict__ cnt)
{
    int i = blockIdx.x * 256 + threadIdx.x;   // grid 256x256 = 65536
    xA[i] = f2bf(emb[i]);
    hA[i] = f2bf(hx[i]);
    cnt[i] = 0;                               // 256 KB of flag lines
}

// ---------------- persistent GRU kernel -------------------------------------
__global__ __launch_bounds__(256, 1) void gru_persistent(
    const unsigned short* __restrict__ Wur, const unsigned short* __restrict__ Wc,
    const float* __restrict__ emb, const float* __restrict__ hx,
    const float* __restrict__ bu, const float* __restrict__ br, const float* __restrict__ bc,
    unsigned short* __restrict__ xA, unsigned short* __restrict__ hA,
    unsigned short* __restrict__ rh, float* __restrict__ out, int* __restrict__ cnt)
{
    __shared__ unsigned short wur_s[32768];   // 64 KB: this WG's 16-col u/r slice
    __shared__ unsigned short wc_s [32768];   // 64 KB: c-WGs' 16-col c slice

    const int wg   = blockIdx.x;
    const int tid  = threadIdx.x;
    const int lane = tid & 63;
    const int wid  = tid >> 6;
    const int m0   = wid * 16;
    const int c15  = lane & 15;
    const int kg   = lane >> 4;

    for (int i = tid; i < 4096; i += 256) {
        int kk = i >> 6, j = i & 63;
        *((uint4*)wur_s + i) =
            *(const uint4*)((const char*)Wur + ((size_t)kk*128 + wg)*1024 + j*16);
    }
    if (wg < 64) {
        for (int i = tid; i < 4096; i += 256) {
            int kk = i >> 6, j = i & 63;
            *((uint4*)wc_s + i) =
                *(const uint4*)((const char*)Wc + ((size_t)kk*64 + wg)*1024 + j*16);
        }
    }
    __syncthreads();

    const int v    = wg & 63;
    const int colj = v * 16 + c15;

    if (wg < 64) {
        // ================= c-path: u + cell + h-update =================
        const float bu_ = bu[colj], bc_ = bc[colj];
        float hreg[4];
        #pragma unroll
        for (int i = 0; i < 4; ++i) hreg[i] = hx[(m0 + kg*4 + i) * DH + colj];

        for (int t = 0; t < T_STEPS; ++t) {
            const int par = t & 1;
            const unsigned short* xa   = xA + par * 65536;
            const unsigned short* ha   = hA + par * 65536;
            unsigned short*       hnxt = hA + (par ^ 1) * 65536;

            f32x4 au = {0.f,0.f,0.f,0.f}, ac = {0.f,0.f,0.f,0.f};
            bf16x8 fr[32];

            // --- x-parts of u and c ---
            if (t) wait_fam(cnt, t, 3, 8);
            const unsigned short* xp = xa + (m0 + c15) * DIN + kg * 8;
            #pragma unroll
            for (int kk = 0; kk < 32; ++kk) fr[kk] = ld_llc(xp + kk * 32);
            vwait0();
            #pragma unroll
            for (int kk = 0; kk < 32; ++kk) {
                au = __builtin_amdgcn_mfma_f32_16x16x32_bf16(
                         fr[kk], *(const bf16x8*)(wur_s + kk*512 + lane*8), au, 0, 0, 0);
                ac = __builtin_amdgcn_mfma_f32_16x16x32_bf16(
                         fr[kk], *(const bf16x8*)(wc_s + kk*512 + lane*8), ac, 0, 0, 0);
            }

            // --- h-part of u ---
            if (t) wait_fam(cnt, t-1, 0, 8);
            const unsigned short* hp = ha + (m0 + c15) * DH + kg * 8;
            #pragma unroll
            for (int kk = 0; kk < 32; ++kk) fr[kk] = ld_llc(hp + kk * 32);
            vwait0();
            #pragma unroll
            for (int kk = 0; kk < 32; ++kk)
                au = __builtin_amdgcn_mfma_f32_16x16x32_bf16(
                         fr[kk], *(const bf16x8*)(wur_s + (kk+32)*512 + lane*8), au, 0, 0, 0);
            float ureg[4];
            #pragma unroll
            for (int i = 0; i < 4; ++i)
                ureg[i] = 1.f / (1.f + __expf(-(au[i] + bu_)));

            // --- rh halves (lo cols 0-511, hi cols 512-1023) ---
            const unsigned short* rp = rh + (m0 + c15) * DH + kg * 8;
            wait_fam(cnt, t, 1, 4);
            #pragma unroll
            for (int kk = 0; kk < 16; ++kk) fr[kk] = ld_llc(rp + kk * 32);
            vwait0();
            #pragma unroll
            for (int kk = 0; kk < 16; ++kk)
                ac = __builtin_amdgcn_mfma_f32_16x16x32_bf16(
                         fr[kk], *(const bf16x8*)(wc_s + (kk+32)*512 + lane*8), ac, 0, 0, 0);
            wait_fam(cnt, t, 2, 4);
            #pragma unroll
            for (int kk = 16; kk < 32; ++kk) fr[kk] = ld_llc(rp + kk * 32);
            vwait0();
            #pragma unroll
            for (int kk = 16; kk < 32; ++kk)
                ac = __builtin_amdgcn_mfma_f32_16x16x32_bf16(
                         fr[kk], *(const bf16x8*)(wc_s + (kk+32)*512 + lane*8), ac, 0, 0, 0);

            // --- update + publish h ---
            float* out_t = out + (size_t)t * (BATCH * DH);
            #pragma unroll
            for (int i = 0; i < 4; ++i) {
                int row = m0 + kg * 4 + i;
                float pre = ac[i] + bc_;
                float e   = __expf(2.f * pre);
                float cel = 1.f - 2.f / (e + 1.f);          // tanh
                float hn  = (1.f - ureg[i]) * hreg[i] + ureg[i] * cel;
                hreg[i] = hn;
                out_t[row * DH + colj] = hn;                // normal store
                st_wt_u16(hnxt + row * DH + colj, (unsigned)f2bf(hn));
                if (t == T_STEPS - 1)
                    out[(size_t)T_STEPS * BATCH * DH + row * DH + colj] = hn;
            }
            asm volatile("s_waitcnt vmcnt(0)" ::: "memory");
            __syncthreads();
            if (tid == 0) post_fam(cnt, t, wg >> 3, 0);
        }
    } else {
        // ================= r-path: reset gate + x conversion =================
        const float br_ = br[colj];
        for (int t = 0; t < T_STEPS; ++t) {
            const int par = t & 1;
            const unsigned short* xa = xA + par * 65536;
            const unsigned short* ha = hA + par * 65536;

            f32x4 ar = {0.f,0.f,0.f,0.f};
            bf16x8 fr[32];

            // --- x-part of r ---
            if (t) wait_fam(cnt, t, 3, 8);
            const unsigned short* xp = xa + (m0 + c15) * DIN + kg * 8;
            #pragma unroll
            for (int kk = 0; kk < 32; ++kk) fr[kk] = ld_llc(xp + kk * 32);
            vwait0();
            #pragma unroll
            for (int kk = 0; kk < 32; ++kk)
                ar = __builtin_amdgcn_mfma_f32_16x16x32_bf16(
                         fr[kk], *(const bf16x8*)(wur_s + kk*512 + lane*8), ar, 0, 0, 0);

            // --- h-part of r (+ own-col h values for rst*h) ---
            if (t) wait_fam(cnt, t-1, 0, 8);
            const unsigned short* hp = ha + (m0 + c15) * DH + kg * 8;
            unsigned hp16[4];
            #pragma unroll
            for (int kk = 0; kk < 32; ++kk) fr[kk] = ld_llc(hp + kk * 32);
            #pragma unroll
            for (int i = 0; i < 4; ++i)
                hp16[i] = ld_llc_u16(ha + (m0 + kg*4 + i) * DH + colj);
            vwait0();
            #pragma unroll
            for (int kk = 0; kk < 32; ++kk)
                ar = __builtin_amdgcn_mfma_f32_16x16x32_bf16(
                         fr[kk], *(const bf16x8*)(wur_s + (kk+32)*512 + lane*8), ar, 0, 0, 0);

            // --- publish rh ---
            #pragma unroll
            for (int i = 0; i < 4; ++i) {
                int row = m0 + kg * 4 + i;
                float s = 1.f / (1.f + __expf(-(ar[i] + br_)));
                st_wt_u16(rh + row * DH + colj, (unsigned)f2bf(s * bf2f(hp16[i])));
            }
            asm volatile("s_waitcnt vmcnt(0)" ::: "memory");
            __syncthreads();
            if (tid == 0) {
                if (v < 32) post_fam(cnt, t, v >> 2, 1);
                else        post_fam(cnt, t, (v - 32) >> 2, 2);
            }

            // --- x_{t+1} conversion (off critical path) ---
            if (t + 1 < T_STEPS) {
                int row = m0 + (lane >> 2);
                int c4  = (lane & 3) * 4;
                const float* src = emb + ((size_t)(t + 1) * BATCH + row) * DIN + v * 16 + c4;
                float4 xv = *(const float4*)src;            // read-only input: cached load
                unsigned long long pk =
                      (unsigned long long)f2bf(xv.x)
                    | ((unsigned long long)f2bf(xv.y) << 16)
                    | ((unsigned long long)f2bf(xv.z) << 32)
                    | ((unsigned long long)f2bf(xv.w) << 48);
                st_wt_u64(xA + (par ^ 1) * 65536 + row * DIN + v * 16 + c4, pk);
                asm volatile("s_waitcnt vmcnt(0)" ::: "memory");
                __syncthreads();
                if (tid == 0) post_fam(cnt, t + 1, v >> 3, 3);
            }
        }
    }
}

// ---------------- host launch ----------------------------------------------
extern "C" void kernel_launch(void* const* d_in, const int* in_sizes, int n_in,
                              void* d_out, int out_size, void* d_ws, size_t ws_size,
                              hipStream_t stream)
{
    const float* emb  = (const float*)d_in[0];
    const float* hx   = (const float*)d_in[1];
    const float* wihu = (const float*)d_in[2];
    const float* wihr = (const float*)d_in[3];
    const float* wihc = (const float*)d_in[4];
    const float* whhu = (const float*)d_in[5];
    const float* whhr = (const float*)d_in[6];
    const float* whhc = (const float*)d_in[7];
    const float* bu   = (const float*)d_in[8];
    const float* br   = (const float*)d_in[9];
    const float* bc   = (const float*)d_in[10];
    float* out = (float*)d_out;
    char*  ws  = (char*)d_ws;

    // ws layout (bytes); total 13,500,416 (< 13.76 MB proven in round 0)
    unsigned short* Wur = (unsigned short*)(ws + 0);          // 8 MiB
    unsigned short* Wc  = (unsigned short*)(ws + 8388608);    // 4 MiB
    unsigned short* xA  = (unsigned short*)(ws + 12582912);   // 256 KiB (2 buffers)
    unsigned short* hA  = (unsigned short*)(ws + 12845056);   // 256 KiB (2 buffers)
    unsigned short* rhb = (unsigned short*)(ws + 13107200);   // 128 KiB
    int*            cnt = (int*)(ws + 13238272);              // 256 KiB flag lines

    gru_pack_weights<<<1024, 256, 0, stream>>>(wihu, wihr, wihc, whhu, whhr, whhc, Wur, Wc);
    gru_init<<<256, 256, 0, stream>>>(emb, hx, xA, hA, cnt);
    gru_persistent<<<NWG, 256, 0, stream>>>(Wur, Wc, emb, hx, bu, br, bc,
                                            xA, hA, rhb, out, cnt);
}

// Round 6
// 8339.370 us; speedup vs baseline: 2.0868x; 1.0169x over previous
//
#include <hip/hip_runtime.h>
#include <hip/hip_bf16.h>
#include <stdint.h>

// BayesGRU eval: T=512, B=64, D_IN=1024, D_H=1024.
// Persistent kernel, 128 WGs (1/CU), weights LDS-resident, fence-free
// LLC-coherent transport, per-step flag lines. Round 6: LEADER-ONLY waits
// (round 5 had all 256 threads polling -> LLC port flood).
//   line(t,g) = 64B, g=0..7:  dword0 = H (quota 8)
//                             dword1 = Rlo (quota 4)  dword2 = Rhi (quota 4)
//                             dword3 = X (quota 8)

#define T_STEPS 512
#define BATCH   64
#define DIN     1024
#define DH      1024
#define NWG     128

typedef __attribute__((ext_vector_type(8))) short bf16x8;
typedef __attribute__((ext_vector_type(4))) float f32x4;

static __device__ __forceinline__ unsigned short f2bf(float x) {
    union { float f; uint32_t u; } v; v.f = x;
    uint32_t u = v.u;
    return (unsigned short)((u + 0x7FFFu + ((u >> 16) & 1u)) >> 16);
}
static __device__ __forceinline__ float bf2f(unsigned u) {
    union { uint32_t v; float f; } x; x.v = u << 16; return x.f;
}

// ---- LLC-coherent transport (bypass L1/L2 both sides; no fences ever) ------
static __device__ __forceinline__ void st_wt_u16(void* p, unsigned v) {
    asm volatile("global_store_short %0, %1, off sc0 sc1" :: "v"(p), "v"(v) : "memory");
}
static __device__ __forceinline__ void st_wt_u64(void* p, unsigned long long v) {
    asm volatile("global_store_dwordx2 %0, %1, off sc0 sc1" :: "v"(p), "v"(v) : "memory");
}
static __device__ __forceinline__ bf16x8 ld_llc(const unsigned short* p) {
    bf16x8 r;
    asm volatile("global_load_dwordx4 %0, %1, off sc0 sc1" : "=v"(r) : "v"(p));
    return r;
}
static __device__ __forceinline__ unsigned ld_llc_u16(const unsigned short* p) {
    unsigned r;
    asm volatile("global_load_ushort %0, %1, off sc0 sc1" : "=v"(r) : "v"(p));
    return r;
}
static __device__ __forceinline__ void vwait0() {
    asm volatile("s_waitcnt vmcnt(0)" ::: "memory");
    __builtin_amdgcn_sched_barrier(0);   // rule #18
}

// ---- flag wait/post ---------------------------------------------------------
// cnt line (t,g) = cnt + t*128 + g*16 ints; fam in dword [0..3].
static __device__ __forceinline__ void wait_fam(const int* cnt, int t, int fam, int quota) {
    const int* b = cnt + t * 128 + fam;
    for (;;) {
        int a0,a1,a2,a3,a4,a5,a6,a7;
        asm volatile("global_load_dword %0, %1, off sc0 sc1" : "=v"(a0) : "v"(b));
        asm volatile("global_load_dword %0, %1, off sc0 sc1" : "=v"(a1) : "v"(b+16));
        asm volatile("global_load_dword %0, %1, off sc0 sc1" : "=v"(a2) : "v"(b+32));
        asm volatile("global_load_dword %0, %1, off sc0 sc1" : "=v"(a3) : "v"(b+48));
        asm volatile("global_load_dword %0, %1, off sc0 sc1" : "=v"(a4) : "v"(b+64));
        asm volatile("global_load_dword %0, %1, off sc0 sc1" : "=v"(a5) : "v"(b+80));
        asm volatile("global_load_dword %0, %1, off sc0 sc1" : "=v"(a6) : "v"(b+96));
        asm volatile("global_load_dword %0, %1, off sc0 sc1" : "=v"(a7) : "v"(b+112));
        asm volatile("s_waitcnt vmcnt(0)" ::: "memory");
        __builtin_amdgcn_sched_barrier(0);
        if (a0>=quota && a1>=quota && a2>=quota && a3>=quota &&
            a4>=quota && a5>=quota && a6>=quota && a7>=quota) break;
        __builtin_amdgcn_s_sleep(2);
    }
}
// leader-only wait: ONE single-lane wave polls, workgroup released by barrier
static __device__ __forceinline__ void wg_wait(const int* cnt, int t, int fam, int quota) {
    if (threadIdx.x == 0) wait_fam(cnt, t, fam, quota);
    __syncthreads();
}
static __device__ __forceinline__ void post_fam(int* cnt, int t, int g, int fam) {
    __hip_atomic_fetch_add(cnt + t * 128 + g * 16 + fam, 1,
                           __ATOMIC_RELAXED, __HIP_MEMORY_SCOPE_AGENT);
}

// ---------------- weight packing (layout verified rounds 1-5) ---------------
__global__ __launch_bounds__(256) void gru_pack_weights(
    const float* __restrict__ wihu, const float* __restrict__ wihr,
    const float* __restrict__ wihc, const float* __restrict__ whhu,
    const float* __restrict__ whhr, const float* __restrict__ whhc,
    unsigned short* __restrict__ Wur, unsigned short* __restrict__ Wc)
{
    const int total = 3072 * 2048;
    for (int idx = blockIdx.x * 256 + threadIdx.x; idx < total; idx += gridDim.x * 256) {
        int n = idx >> 11;        // 0..3071
        int k = idx & 2047;
        int j = n & 1023;
        float v;
        if (n < 1024)      v = (k < DIN) ? wihu[j*DIN + k] : whhu[j*DH + (k - DIN)];
        else if (n < 2048) v = (k < DIN) ? wihr[j*DIN + k] : whhr[j*DH + (k - DIN)];
        else               v = (k < DIN) ? wihc[j*DIN + k] : whhc[j*DH + (k - DIN)];
        unsigned short bv = f2bf(v);
        int kk = k >> 5, kg = (k >> 3) & 3, r = k & 7;
        if (n < 2048) {
            int b = n >> 4, col = n & 15;
            Wur[((((size_t)kk*128 + b)*4 + kg)*16 + col)*8 + r] = bv;
        } else {
            int nc = n - 2048, b = nc >> 4, col = nc & 15;
            Wc [((((size_t)kk*64 + b)*4 + kg)*16 + col)*8 + r] = bv;
        }
    }
}

// ---------------- init: xA[0]=bf16(x_0), hA[0]=bf16(h0), counters=0 ---------
__global__ __launch_bounds__(256) void gru_init(
    const float* __restrict__ emb, const float* __restrict__ hx,
    unsigned short* __restrict__ xA, unsigned short* __restrict__ hA,
    int* __restrict__ cnt)
{
    int i = blockIdx.x * 256 + threadIdx.x;   // grid 256x256 = 65536
    xA[i] = f2bf(emb[i]);
    hA[i] = f2bf(hx[i]);
    cnt[i] = 0;                               // 256 KB of flag lines
}

// ---------------- persistent GRU kernel -------------------------------------
__global__ __launch_bounds__(256, 1) void gru_persistent(
    const unsigned short* __restrict__ Wur, const unsigned short* __restrict__ Wc,
    const float* __restrict__ emb, const float* __restrict__ hx,
    const float* __restrict__ bu, const float* __restrict__ br, const float* __restrict__ bc,
    unsigned short* __restrict__ xA, unsigned short* __restrict__ hA,
    unsigned short* __restrict__ rh, float* __restrict__ out, int* __restrict__ cnt)
{
    __shared__ unsigned short wur_s[32768];   // 64 KB: this WG's 16-col u/r slice
    __shared__ unsigned short wc_s [32768];   // 64 KB: c-WGs' 16-col c slice

    const int wg   = blockIdx.x;
    const int tid  = threadIdx.x;
    const int lane = tid & 63;
    const int wid  = tid >> 6;
    const int m0   = wid * 16;
    const int c15  = lane & 15;
    const int kg   = lane >> 4;

    for (int i = tid; i < 4096; i += 256) {
        int kk = i >> 6, j = i & 63;
        *((uint4*)wur_s + i) =
            *(const uint4*)((const char*)Wur + ((size_t)kk*128 + wg)*1024 + j*16);
    }
    if (wg < 64) {
        for (int i = tid; i < 4096; i += 256) {
            int kk = i >> 6, j = i & 63;
            *((uint4*)wc_s + i) =
                *(const uint4*)((const char*)Wc + ((size_t)kk*64 + wg)*1024 + j*16);
        }
    }
    __syncthreads();

    const int v    = wg & 63;
    const int colj = v * 16 + c15;

    if (wg < 64) {
        // ================= c-path: u + cell + h-update =================
        const float bu_ = bu[colj], bc_ = bc[colj];
        float hreg[4];
        #pragma unroll
        for (int i = 0; i < 4; ++i) hreg[i] = hx[(m0 + kg*4 + i) * DH + colj];

        for (int t = 0; t < T_STEPS; ++t) {
            const int par = t & 1;
            const unsigned short* xa   = xA + par * 65536;
            const unsigned short* ha   = hA + par * 65536;
            unsigned short*       hnxt = hA + (par ^ 1) * 65536;

            f32x4 au = {0.f,0.f,0.f,0.f}, ac = {0.f,0.f,0.f,0.f};
            bf16x8 fr[32];

            // --- x-parts of u and c ---
            if (t) wg_wait(cnt, t, 3, 8);
            const unsigned short* xp = xa + (m0 + c15) * DIN + kg * 8;
            #pragma unroll
            for (int kk = 0; kk < 32; ++kk) fr[kk] = ld_llc(xp + kk * 32);
            vwait0();
            #pragma unroll
            for (int kk = 0; kk < 32; ++kk) {
                au = __builtin_amdgcn_mfma_f32_16x16x32_bf16(
                         fr[kk], *(const bf16x8*)(wur_s + kk*512 + lane*8), au, 0, 0, 0);
                ac = __builtin_amdgcn_mfma_f32_16x16x32_bf16(
                         fr[kk], *(const bf16x8*)(wc_s + kk*512 + lane*8), ac, 0, 0, 0);
            }

            // --- h-part of u ---
            if (t) wg_wait(cnt, t-1, 0, 8);
            const unsigned short* hp = ha + (m0 + c15) * DH + kg * 8;
            #pragma unroll
            for (int kk = 0; kk < 32; ++kk) fr[kk] = ld_llc(hp + kk * 32);
            vwait0();
            #pragma unroll
            for (int kk = 0; kk < 32; ++kk)
                au = __builtin_amdgcn_mfma_f32_16x16x32_bf16(
                         fr[kk], *(const bf16x8*)(wur_s + (kk+32)*512 + lane*8), au, 0, 0, 0);
            float ureg[4];
            #pragma unroll
            for (int i = 0; i < 4; ++i)
                ureg[i] = 1.f / (1.f + __expf(-(au[i] + bu_)));

            // --- rh halves (lo cols 0-511, hi cols 512-1023) ---
            const unsigned short* rp = rh + (m0 + c15) * DH + kg * 8;
            wg_wait(cnt, t, 1, 4);
            #pragma unroll
            for (int kk = 0; kk < 16; ++kk) fr[kk] = ld_llc(rp + kk * 32);
            vwait0();
            #pragma unroll
            for (int kk = 0; kk < 16; ++kk)
                ac = __builtin_amdgcn_mfma_f32_16x16x32_bf16(
                         fr[kk], *(const bf16x8*)(wc_s + (kk+32)*512 + lane*8), ac, 0, 0, 0);
            wg_wait(cnt, t, 2, 4);
            #pragma unroll
            for (int kk = 16; kk < 32; ++kk) fr[kk] = ld_llc(rp + kk * 32);
            vwait0();
            #pragma unroll
            for (int kk = 16; kk < 32; ++kk)
                ac = __builtin_amdgcn_mfma_f32_16x16x32_bf16(
                         fr[kk], *(const bf16x8*)(wc_s + (kk+32)*512 + lane*8), ac, 0, 0, 0);

            // --- update + publish h ---
            float* out_t = out + (size_t)t * (BATCH * DH);
            #pragma unroll
            for (int i = 0; i < 4; ++i) {
                int row = m0 + kg * 4 + i;
                float pre = ac[i] + bc_;
                float e   = __expf(2.f * pre);
                float cel = 1.f - 2.f / (e + 1.f);          // tanh
                float hn  = (1.f - ureg[i]) * hreg[i] + ureg[i] * cel;
                hreg[i] = hn;
                out_t[row * DH + colj] = hn;                // normal store
                st_wt_u16(hnxt + row * DH + colj, (unsigned)f2bf(hn));
                if (t == T_STEPS - 1)
                    out[(size_t)T_STEPS * BATCH * DH + row * DH + colj] = hn;
            }
            asm volatile("s_waitcnt vmcnt(0)" ::: "memory");
            __syncthreads();
            if (tid == 0) post_fam(cnt, t, wg >> 3, 0);
        }
    } else {
        // ================= r-path: reset gate + x conversion =================
        const float br_ = br[colj];
        for (int t = 0; t < T_STEPS; ++t) {
            const int par = t & 1;
            const unsigned short* xa = xA + par * 65536;
            const unsigned short* ha = hA + par * 65536;

            f32x4 ar = {0.f,0.f,0.f,0.f};
            bf16x8 fr[32];

            // --- x-part of r ---
            if (t) wg_wait(cnt, t, 3, 8);
            const unsigned short* xp = xa + (m0 + c15) * DIN + kg * 8;
            #pragma unroll
            for (int kk = 0; kk < 32; ++kk) fr[kk] = ld_llc(xp + kk * 32);
            vwait0();
            #pragma unroll
            for (int kk = 0; kk < 32; ++kk)
                ar = __builtin_amdgcn_mfma_f32_16x16x32_bf16(
                         fr[kk], *(const bf16x8*)(wur_s + kk*512 + lane*8), ar, 0, 0, 0);

            // --- h-part of r (+ own-col h values for rst*h) ---
            if (t) wg_wait(cnt, t-1, 0, 8);
            const unsigned short* hp = ha + (m0 + c15) * DH + kg * 8;
            unsigned hp16[4];
            #pragma unroll
            for (int kk = 0; kk < 32; ++kk) fr[kk] = ld_llc(hp + kk * 32);
            #pragma unroll
            for (int i = 0; i < 4; ++i)
                hp16[i] = ld_llc_u16(ha + (m0 + kg*4 + i) * DH + colj);
            vwait0();
            #pragma unroll
            for (int kk = 0; kk < 32; ++kk)
                ar = __builtin_amdgcn_mfma_f32_16x16x32_bf16(
                         fr[kk], *(const bf16x8*)(wur_s + (kk+32)*512 + lane*8), ar, 0, 0, 0);

            // --- publish rh ---
            #pragma unroll
            for (int i = 0; i < 4; ++i) {
                int row = m0 + kg * 4 + i;
                float s = 1.f / (1.f + __expf(-(ar[i] + br_)));
                st_wt_u16(rh + row * DH + colj, (unsigned)f2bf(s * bf2f(hp16[i])));
            }
            asm volatile("s_waitcnt vmcnt(0)" ::: "memory");
            __syncthreads();
            if (tid == 0) {
                if (v < 32) post_fam(cnt, t, v >> 2, 1);
                else        post_fam(cnt, t, (v - 32) >> 2, 2);
            }

            // --- x_{t+1} conversion (off critical path) ---
            if (t + 1 < T_STEPS) {
                int row = m0 + (lane >> 2);
                int c4  = (lane & 3) * 4;
                const float* src = emb + ((size_t)(t + 1) * BATCH + row) * DIN + v * 16 + c4;
                float4 xv = *(const float4*)src;            // read-only input: cached load
                unsigned long long pk =
                      (unsigned long long)f2bf(xv.x)
                    | ((unsigned long long)f2bf(xv.y) << 16)
                    | ((unsigned long long)f2bf(xv.z) << 32)
                    | ((unsigned long long)f2bf(xv.w) << 48);
                st_wt_u64(xA + (par ^ 1) * 65536 + row * DIN + v * 16 + c4, pk);
                asm volatile("s_waitcnt vmcnt(0)" ::: "memory");
                __syncthreads();
                if (tid == 0) post_fam(cnt, t + 1, v >> 3, 3);
            }
        }
    }
}

// ---------------- host launch ----------------------------------------------
extern "C" void kernel_launch(void* const* d_in, const int* in_sizes, int n_in,
                              void* d_out, int out_size, void* d_ws, size_t ws_size,
                              hipStream_t stream)
{
    const float* emb  = (const float*)d_in[0];
    const float* hx   = (const float*)d_in[1];
    const float* wihu = (const float*)d_in[2];
    const float* wihr = (const float*)d_in[3];
    const float* wihc = (const float*)d_in[4];
    const float* whhu = (const float*)d_in[5];
    const float* whhr = (const float*)d_in[6];
    const float* whhc = (const float*)d_in[7];
    const float* bu   = (const float*)d_in[8];
    const float* br   = (const float*)d_in[9];
    const float* bc   = (const float*)d_in[10];
    float* out = (float*)d_out;
    char*  ws  = (char*)d_ws;

    // ws layout (bytes); total 13,500,416 (< 13.76 MB proven in round 0)
    unsigned short* Wur = (unsigned short*)(ws + 0);          // 8 MiB
    unsigned short* Wc  = (unsigned short*)(ws + 8388608);    // 4 MiB
    unsigned short* xA  = (unsigned short*)(ws + 12582912);   // 256 KiB (2 buffers)
    unsigned short* hA  = (unsigned short*)(ws + 12845056);   // 256 KiB (2 buffers)
    unsigned short* rhb = (unsigned short*)(ws + 13107200);   // 128 KiB
    int*            cnt = (int*)(ws + 13238272);              // 256 KiB flag lines

    gru_pack_weights<<<1024, 256, 0, stream>>>(wihu, wihr, wihc, whhu, whhr, whhc, Wur, Wc);
    gru_init<<<256, 256, 0, stream>>>(emb, hx, xA, hA, cnt);
    gru_persistent<<<NWG, 256, 0, stream>>>(Wur, Wc, emb, hx, bu, br, bc,
                                            xA, hA, rhb, out, cnt);
}